// Round 1
// baseline (526.732 us; speedup 1.0000x reference)
//
#include <hip/hip_runtime.h>
#include <math.h>

// Problem constants (B, Lc, Lq, D fixed by setup_inputs)
constexpr int Bn = 64, Lc = 1024, Lq = 128, Dd = 128;

// workspace layout in floats
constexpr size_t OFF_E   = 0;                                  // B*Lc*Lq  exp(S)
constexpr size_t OFF_COL = OFF_E   + (size_t)Bn * Lc * Lq;     // B*Lq     col sums (masked)
constexpr size_t OFF_T   = OFF_COL + (size_t)Bn * Lq;          // B*Lq*D   T = S2^T @ C
constexpr size_t OFF_S0C = OFF_T   + (size_t)Bn * Lq * Dd;     // B*Lc     C.w_c
constexpr size_t OFF_S1Q = OFF_S0C + (size_t)Bn * Lc;          // B*Lq     Q.w_q

// ---------------- K0: s0c[b,i] = C[b,i,:].w_c ; s1q[b,j] = Q[b,j,:].w_q ----------------
__global__ __launch_bounds__(128) void k0_dots(
    const float* __restrict__ C, const float* __restrict__ Q,
    const float* __restrict__ w_c, const float* __restrict__ w_q,
    float* __restrict__ s0c, float* __restrict__ s1q)
{
    int r = blockIdx.x;
    int d = threadIdx.x;
    float v;
    if (r < Bn * Lc) v = C[(size_t)r * Dd + d] * w_c[d];
    else             v = Q[(size_t)(r - Bn * Lc) * Dd + d] * w_q[d];
    #pragma unroll
    for (int off = 32; off > 0; off >>= 1) v += __shfl_down(v, off);
    __shared__ float sred[2];
    int lane = threadIdx.x & 63, wv = threadIdx.x >> 6;
    if (lane == 0) sred[wv] = v;
    __syncthreads();
    if (threadIdx.x == 0) {
        float t = sred[0] + sred[1];
        if (r < Bn * Lc) s0c[r] = t;
        else             s1q[r - Bn * Lc] = t;
    }
}

// ---------------- K1: E[b,i,j] = exp(S[b,i,j]); colsum[b,j] += Cmask*E ----------------
// block: 256 threads handles (b, 64 rows i). thread = (j in 0..127, ih in 0..1) -> 32 i each.
__global__ __launch_bounds__(256) void k1_scores(
    const float* __restrict__ C, const float* __restrict__ Q,
    const int* __restrict__ Cmask,
    const float* __restrict__ w_mul, const float* __restrict__ bias,
    const float* __restrict__ s0c, const float* __restrict__ s1q,
    float* __restrict__ E, float* __restrict__ colsum)
{
    __shared__ __align__(16) float CW[64 * 128];
    __shared__ float s0L[64];
    __shared__ float cmL[64];
    int b  = blockIdx.y;
    int i0 = blockIdx.x * 64;
    int tid = threadIdx.x;

    #pragma unroll
    for (int k = 0; k < 32; ++k) {
        int idx = tid + k * 256;
        int il = idx >> 7, d = idx & 127;
        CW[idx] = C[((size_t)(b * Lc + i0 + il)) * Dd + d] * w_mul[d];
    }
    if (tid < 64) {
        s0L[tid] = s0c[b * Lc + i0 + tid];
        cmL[tid] = (Cmask[b * Lc + i0 + tid] != 0) ? 1.0f : 0.0f;
    }
    __syncthreads();

    int j = tid & 127, ih = tid >> 7;
    float acc[32];
    #pragma unroll
    for (int ii = 0; ii < 32; ++ii) acc[ii] = 0.0f;

    const float4* Qrow = (const float4*)(Q + ((size_t)(b * Lq + j)) * Dd);
    const float4* CW4  = (const float4*)CW;
    for (int d4 = 0; d4 < 32; ++d4) {
        float4 q = Qrow[d4];
        #pragma unroll
        for (int ii = 0; ii < 32; ++ii) {
            float4 c = CW4[(ih * 32 + ii) * 32 + d4]; // broadcast across wave (same addr) - conflict-free
            acc[ii] = fmaf(c.x, q.x, acc[ii]);
            acc[ii] = fmaf(c.y, q.y, acc[ii]);
            acc[ii] = fmaf(c.z, q.z, acc[ii]);
            acc[ii] = fmaf(c.w, q.w, acc[ii]);
        }
    }

    float s1b = s1q[b * Lq + j] + bias[0];
    float colpart = 0.0f;
    #pragma unroll
    for (int ii = 0; ii < 32; ++ii) {
        int il = ih * 32 + ii;
        float s = acc[ii] + s0L[il] + s1b;
        float e = __expf(s);                 // |s| <~ 35 for this input distribution: safe in f32
        E[((size_t)(b * Lc + i0 + il)) * Lq + j] = e;
        colpart += cmL[il] * e;
    }
    atomicAdd(&colsum[b * Lq + j], colpart);
}

// ---------------- K2: T[b,j,d] = sum_i Cmask*E[b,i,j]*C[b,i,d] / colsum[b,j] ----------------
// block: (d-tile of 16, b). 256 threads: dl=tid&15, jg=tid>>4 -> 8 j per thread.
__global__ __launch_bounds__(256) void k2_T(
    const float* __restrict__ C, const int* __restrict__ Cmask,
    const float* __restrict__ E, const float* __restrict__ colsum,
    float* __restrict__ T)
{
    __shared__ __align__(16) float Es[32 * 128];
    __shared__ float Cs[32 * 16];
    int b = blockIdx.y;
    int dbase = blockIdx.x * 16;
    int tid = threadIdx.x;
    int dl = tid & 15, jg = tid >> 4;

    float acc[8];
    #pragma unroll
    for (int t = 0; t < 8; ++t) acc[t] = 0.0f;

    for (int ic = 0; ic < 32; ++ic) {
        #pragma unroll
        for (int k = 0; k < 16; ++k) {
            int idx = tid + k * 256;
            int row = idx >> 7, col = idx & 127;
            int i = ic * 32 + row;
            float cmv = (Cmask[b * Lc + i] != 0) ? 1.0f : 0.0f;
            Es[idx] = cmv * E[((size_t)(b * Lc + i)) * Lq + col];
        }
        #pragma unroll
        for (int k = 0; k < 2; ++k) {
            int idx = tid + k * 256;
            int row = idx >> 4, c = idx & 15;
            Cs[idx] = C[((size_t)(b * Lc + ic * 32 + row)) * Dd + dbase + c];
        }
        __syncthreads();
        const float4* Es4 = (const float4*)Es;
        #pragma unroll 4
        for (int ii = 0; ii < 32; ++ii) {
            float cv = Cs[ii * 16 + dl];
            #pragma unroll
            for (int j4 = 0; j4 < 2; ++j4) {
                float4 e = Es4[ii * 32 + jg * 2 + j4];
                acc[j4 * 4 + 0] = fmaf(e.x, cv, acc[j4 * 4 + 0]);
                acc[j4 * 4 + 1] = fmaf(e.y, cv, acc[j4 * 4 + 1]);
                acc[j4 * 4 + 2] = fmaf(e.z, cv, acc[j4 * 4 + 2]);
                acc[j4 * 4 + 3] = fmaf(e.w, cv, acc[j4 * 4 + 3]);
            }
        }
        __syncthreads();
    }
    #pragma unroll
    for (int jj = 0; jj < 8; ++jj) {
        int j = jg * 8 + jj;
        T[((size_t)(b * Lq + j)) * Dd + dbase + dl] = acc[jj] / colsum[b * Lq + j];
    }
}

// ---------------- K3: row softmax + A = S1@Q, Bm = S1@T, write [C, A, C*A, C*Bm] ----------------
// block: (i-tile of 32, b). 256 threads: d=tid&127, ih=tid>>7 -> 16 i each.
__global__ __launch_bounds__(256) void k3_out(
    const float* __restrict__ C, const float* __restrict__ Q,
    const int* __restrict__ Qmask,
    const float* __restrict__ E, const float* __restrict__ T,
    float* __restrict__ out)
{
    __shared__ float P1[32 * 128];
    __shared__ float rs[32];
    int b = blockIdx.y;
    int i0 = blockIdx.x * 32;
    int tid = threadIdx.x;

    #pragma unroll
    for (int k = 0; k < 16; ++k) {
        int idx = tid + k * 256;
        int row = idx >> 7, col = idx & 127;
        float e = E[((size_t)(b * Lc + i0 + row)) * Lq + col];
        P1[idx] = (Qmask[b * Lq + col] != 0) ? e : 0.0f;
    }
    if (tid < 32) rs[tid] = 0.0f;
    __syncthreads();
    {
        int row = tid >> 3, seg = tid & 7;
        float part = 0.0f;
        #pragma unroll
        for (int k = 0; k < 16; ++k) part += P1[row * 128 + seg * 16 + k];
        atomicAdd(&rs[row], part);
    }
    __syncthreads();
    if (tid < 32) rs[tid] = 1.0f / rs[tid];
    __syncthreads();

    int d = tid & 127, ih = tid >> 7;
    float accA[16], accB[16];
    #pragma unroll
    for (int ii = 0; ii < 16; ++ii) { accA[ii] = 0.0f; accB[ii] = 0.0f; }

    const float* Qb = Q + (size_t)b * Lq * Dd;
    const float* Tb = T + (size_t)b * Lq * Dd;
    for (int j = 0; j < Lq; ++j) {
        float q = Qb[j * Dd + d];
        float t = Tb[j * Dd + d];
        #pragma unroll
        for (int ii = 0; ii < 16; ++ii) {
            float p = P1[(ih * 16 + ii) * 128 + j]; // wave-uniform broadcast read
            accA[ii] = fmaf(p, q, accA[ii]);
            accB[ii] = fmaf(p, t, accB[ii]);
        }
    }

    #pragma unroll
    for (int ii = 0; ii < 16; ++ii) {
        int il = ih * 16 + ii;
        int i = i0 + il;
        float inv = rs[il];
        float a  = accA[ii] * inv;
        float bm = accB[ii] * inv;
        float cv = C[((size_t)(b * Lc + i)) * Dd + d];
        size_t base = ((size_t)(b * Lc + i)) * (4 * Dd);
        out[base + 0 * Dd + d] = cv;
        out[base + 1 * Dd + d] = a;
        out[base + 2 * Dd + d] = cv * a;
        out[base + 3 * Dd + d] = cv * bm;
    }
}

extern "C" void kernel_launch(void* const* d_in, const int* in_sizes, int n_in,
                              void* d_out, int out_size, void* d_ws, size_t ws_size,
                              hipStream_t stream) {
    const float* C     = (const float*)d_in[0];
    const float* Q     = (const float*)d_in[1];
    const int*   Cmask = (const int*)d_in[2];
    const int*   Qmask = (const int*)d_in[3];
    const float* w_c   = (const float*)d_in[4];
    const float* w_q   = (const float*)d_in[5];
    const float* w_mul = (const float*)d_in[6];
    const float* bias  = (const float*)d_in[7];
    float* out = (float*)d_out;

    float* ws     = (float*)d_ws;
    float* E      = ws + OFF_E;
    float* colsum = ws + OFF_COL;
    float* T      = ws + OFF_T;
    float* s0c    = ws + OFF_S0C;
    float* s1q    = ws + OFF_S1Q;

    hipMemsetAsync(colsum, 0, (size_t)Bn * Lq * sizeof(float), stream);
    k0_dots<<<dim3(Bn * Lc + Bn * Lq), dim3(128), 0, stream>>>(C, Q, w_c, w_q, s0c, s1q);
    k1_scores<<<dim3(Lc / 64, Bn), dim3(256), 0, stream>>>(C, Q, Cmask, w_mul, bias, s0c, s1q, E, colsum);
    k2_T<<<dim3(Dd / 16, Bn), dim3(256), 0, stream>>>(C, Cmask, E, colsum, T);
    k3_out<<<dim3(Lc / 32, Bn), dim3(256), 0, stream>>>(C, Q, Qmask, E, T, out);
}

// Round 2
// 323.470 us; speedup vs baseline: 1.6284x; 1.6284x over previous
//
#include <hip/hip_runtime.h>
#include <math.h>

// Problem constants
constexpr int Bn = 64, Lc = 1024, Lq = 128, Dd = 128;

typedef __attribute__((ext_vector_type(8))) short short8_t;  // 8 bf16
typedef __attribute__((ext_vector_type(4))) short short4_t;  // 4 bf16
typedef __attribute__((ext_vector_type(4))) float f32x4;

__device__ __forceinline__ short f2bf(float x) {
    unsigned u = __float_as_uint(x);
    u += 0x7FFFu + ((u >> 16) & 1u);   // round-to-nearest-even
    return (short)(u >> 16);
}

// ---------------- kP: prep bf16 operands + row dots ----------------
// blockIdx.x 0..15: C-tile (64 rows) -> Cw16 [b,i,d], CT16 [b,d,i] (cmask-folded), s0c
// blockIdx.x == 16: Q       -> Q16 [b,j,d], QT16 [b,d,j] (qmask-folded), s1q
__global__ __launch_bounds__(256) void kP_prep(
    const float* __restrict__ C, const float* __restrict__ Q,
    const int* __restrict__ Cmask, const int* __restrict__ Qmask,
    const float* __restrict__ w_c, const float* __restrict__ w_q,
    const float* __restrict__ w_mul,
    short* __restrict__ Cw16, short* __restrict__ CT16,
    short* __restrict__ Q16, short* __restrict__ QT16,
    float* __restrict__ s0c, float* __restrict__ s1q)
{
    __shared__ short lds[128 * 132];
    int b = blockIdx.y, x = blockIdx.x, tid = threadIdx.x;

    if (x < 16) {
        int i0 = x * 64;
        const float4* C4 = (const float4*)(C + ((size_t)(b * Lc + i0)) * Dd);
        #pragma unroll
        for (int k = 0; k < 8; ++k) {
            int idx = tid + k * 256;            // 2048 float4 = 64 rows x 32
            int i = idx >> 5, d4 = idx & 31;
            float4 v = C4[idx];
            float4 wm = ((const float4*)w_mul)[d4];
            short4_t cw; cw[0]=f2bf(v.x*wm.x); cw[1]=f2bf(v.y*wm.y); cw[2]=f2bf(v.z*wm.z); cw[3]=f2bf(v.w*wm.w);
            *(short4_t*)&Cw16[((size_t)(b * Lc + i0 + i)) * Dd + d4 * 4] = cw;
            float cm = (Cmask[b * Lc + i0 + i] != 0) ? 1.0f : 0.0f;
            lds[(d4*4+0)*68 + i] = f2bf(cm * v.x);
            lds[(d4*4+1)*68 + i] = f2bf(cm * v.y);
            lds[(d4*4+2)*68 + i] = f2bf(cm * v.z);
            lds[(d4*4+3)*68 + i] = f2bf(cm * v.w);
            float4 wc = ((const float4*)w_c)[d4];
            float dot = v.x*wc.x + v.y*wc.y + v.z*wc.z + v.w*wc.w;
            #pragma unroll
            for (int off = 1; off < 32; off <<= 1) dot += __shfl_xor(dot, off, 64);
            if ((tid & 31) == 0) s0c[b * Lc + i0 + i] = dot;
        }
        __syncthreads();
        #pragma unroll
        for (int k = 0; k < 8; ++k) {
            int idx = tid + k * 256;            // 2048 short4 = 128 d x 16
            int d = idx >> 4, i4 = idx & 15;
            *(short4_t*)&CT16[((size_t)(b * Lq + d)) * Lc + i0 + i4 * 4] =
                *(short4_t*)&lds[d * 68 + i4 * 4];
        }
    } else {
        const float4* Q4 = (const float4*)(Q + (size_t)b * Lq * Dd);
        #pragma unroll
        for (int k = 0; k < 16; ++k) {
            int idx = tid + k * 256;            // 4096 float4 = 128 rows x 32
            int j = idx >> 5, d4 = idx & 31;
            float4 v = Q4[idx];
            short4_t qv; qv[0]=f2bf(v.x); qv[1]=f2bf(v.y); qv[2]=f2bf(v.z); qv[3]=f2bf(v.w);
            *(short4_t*)&Q16[((size_t)(b * Lq + j)) * Dd + d4 * 4] = qv;
            float qm = (Qmask[b * Lq + j] != 0) ? 1.0f : 0.0f;
            lds[(d4*4+0)*132 + j] = f2bf(qm * v.x);
            lds[(d4*4+1)*132 + j] = f2bf(qm * v.y);
            lds[(d4*4+2)*132 + j] = f2bf(qm * v.z);
            lds[(d4*4+3)*132 + j] = f2bf(qm * v.w);
            float4 wq = ((const float4*)w_q)[d4];
            float dot = v.x*wq.x + v.y*wq.y + v.z*wq.z + v.w*wq.w;
            #pragma unroll
            for (int off = 1; off < 32; off <<= 1) dot += __shfl_xor(dot, off, 64);
            if ((tid & 31) == 0) s1q[b * Lq + j] = dot;
        }
        __syncthreads();
        #pragma unroll
        for (int k = 0; k < 16; ++k) {
            int idx = tid + k * 256;            // 4096 short4 = 128 d x 32
            int d = idx >> 5, j4 = idx & 31;
            *(short4_t*)&QT16[((size_t)(b * Lq + d)) * Lq + j4 * 4] =
                *(short4_t*)&lds[d * 132 + j4 * 4];
        }
    }
}

// ---------------- k1: S = Cw @ Q^T (MFMA), E = exp(S), colsum, rowsumInv ----------------
// grid (Lc/64, B). 4 waves; wave w: i-subtile [i0+16w, +16), all 8 j-subtiles.
__global__ __launch_bounds__(256) void k1_scores(
    const short* __restrict__ Cw16, const short* __restrict__ Q16,
    const int* __restrict__ Cmask, const int* __restrict__ Qmask,
    const float* __restrict__ s0c, const float* __restrict__ s1q,
    const float* __restrict__ bias,
    short* __restrict__ E16, short* __restrict__ ET16,
    float* __restrict__ colsum, float* __restrict__ rowsumInv)
{
    int b = blockIdx.y, i0 = blockIdx.x * 64;
    int tid = threadIdx.x, w = tid >> 6, lane = tid & 63;
    int lm = lane & 15, quad = lane >> 4;
    int iw = i0 + w * 16;

    f32x4 acc[8];
    #pragma unroll
    for (int t = 0; t < 8; ++t) acc[t] = (f32x4){0.f,0.f,0.f,0.f};

    const short8_t* Arow = (const short8_t*)(Cw16 + ((size_t)(b * Lc + iw + lm)) * Dd);
    const short8_t* Brow[8];
    #pragma unroll
    for (int jt = 0; jt < 8; ++jt)
        Brow[jt] = (const short8_t*)(Q16 + ((size_t)(b * Lq + jt * 16 + lm)) * Dd);

    #pragma unroll
    for (int ks = 0; ks < 4; ++ks) {
        short8_t a = Arow[ks * 4 + quad];
        #pragma unroll
        for (int jt = 0; jt < 8; ++jt) {
            short8_t bf = Brow[jt][ks * 4 + quad];
            acc[jt] = __builtin_amdgcn_mfma_f32_16x16x32_bf16(a, bf, acc[jt], 0, 0, 0);
        }
    }

    float s0[4], cm[4];
    #pragma unroll
    for (int r = 0; r < 4; ++r) {
        int i = iw + quad * 4 + r;
        s0[r] = s0c[b * Lc + i];
        cm[r] = (Cmask[b * Lc + i] != 0) ? 1.0f : 0.0f;
    }
    float bb = bias[0];
    float rowpart[4] = {0.f, 0.f, 0.f, 0.f};

    #pragma unroll
    for (int jt = 0; jt < 8; ++jt) {
        int j = jt * 16 + lm;
        float s1 = s1q[b * Lq + j] + bb;
        float qm = (Qmask[b * Lq + j] != 0) ? 1.0f : 0.0f;
        float cs = 0.f;
        short4_t etp;
        #pragma unroll
        for (int r = 0; r < 4; ++r) {
            float e = __expf(acc[jt][r] + s0[r] + s1);
            E16[((size_t)(b * Lc + iw + quad * 4 + r)) * Lq + j] = f2bf(e);
            etp[r] = f2bf(e);
            rowpart[r] += qm * e;
            cs += cm[r] * e;
        }
        *(short4_t*)&ET16[((size_t)(b * Lq + j)) * Lc + iw + quad * 4] = etp;
        cs += __shfl_xor(cs, 16, 64);
        cs += __shfl_xor(cs, 32, 64);
        if (lane < 16) atomicAdd(&colsum[b * Lq + j], cs);
    }
    #pragma unroll
    for (int r = 0; r < 4; ++r) {
        float v = rowpart[r];
        v += __shfl_xor(v, 1, 64); v += __shfl_xor(v, 2, 64);
        v += __shfl_xor(v, 4, 64); v += __shfl_xor(v, 8, 64);
        if (lm == 0) rowsumInv[b * Lc + iw + quad * 4 + r] = 1.0f / v;
    }
}

// ---------------- k2: Tpart[j,d] += sum_i E[i,j] * (cm*C)[i,d] over K-slice (MFMA) ----------------
// grid (4 k-chunks, B). wave w: j-subtiles {2w,2w+1} x 8 d-subtiles.
__global__ __launch_bounds__(256) void k2_T(
    const short* __restrict__ ET16, const short* __restrict__ CT16,
    float* __restrict__ T32)
{
    int b = blockIdx.y, kc = blockIdx.x;
    int tid = threadIdx.x, w = tid >> 6, lane = tid & 63;
    int lm = lane & 15, quad = lane >> 4;

    f32x4 acc[2][8];
    #pragma unroll
    for (int jj = 0; jj < 2; ++jj)
        #pragma unroll
        for (int dt = 0; dt < 8; ++dt) acc[jj][dt] = (f32x4){0.f,0.f,0.f,0.f};

    #pragma unroll
    for (int ks = 0; ks < 8; ++ks) {
        int gk = kc * 256 + ks * 32 + quad * 8;
        short8_t a[2];
        #pragma unroll
        for (int jj = 0; jj < 2; ++jj)
            a[jj] = *(const short8_t*)&ET16[((size_t)(b * Lq + (w * 2 + jj) * 16 + lm)) * Lc + gk];
        #pragma unroll
        for (int dt = 0; dt < 8; ++dt) {
            short8_t bf = *(const short8_t*)&CT16[((size_t)(b * Lq + dt * 16 + lm)) * Lc + gk];
            #pragma unroll
            for (int jj = 0; jj < 2; ++jj)
                acc[jj][dt] = __builtin_amdgcn_mfma_f32_16x16x32_bf16(a[jj], bf, acc[jj][dt], 0, 0, 0);
        }
    }
    #pragma unroll
    for (int jj = 0; jj < 2; ++jj)
        #pragma unroll
        for (int dt = 0; dt < 8; ++dt)
            #pragma unroll
            for (int r = 0; r < 4; ++r) {
                int j = (w * 2 + jj) * 16 + quad * 4 + r;
                atomicAdd(&T32[((size_t)(b * Lq + j)) * Dd + dt * 16 + lm], acc[jj][dt][r]);
            }
}

// ---------------- k2b: TT16[d,j] = bf16( qm[j] * T32[j,d] / colsum[j] ) ----------------
__global__ __launch_bounds__(256) void k2b_finish(
    const float* __restrict__ T32, const float* __restrict__ colsum,
    const int* __restrict__ Qmask, short* __restrict__ TT16)
{
    __shared__ short lds[128 * 132];
    __shared__ float invq[128];
    int b = blockIdx.x, tid = threadIdx.x;
    if (tid < 128) {
        float cs = colsum[b * Lq + tid];
        invq[tid] = (Qmask[b * Lq + tid] != 0) ? (1.0f / cs) : 0.0f;
    }
    __syncthreads();
    #pragma unroll
    for (int k = 0; k < 64; ++k) {
        int idx = tid + k * 256;                // 16384 = 128 j x 128 d
        int j = idx >> 7, d = idx & 127;
        float v = T32[((size_t)(b * Lq + j)) * Dd + d] * invq[j];
        lds[d * 132 + j] = f2bf(v);
    }
    __syncthreads();
    #pragma unroll
    for (int k = 0; k < 16; ++k) {
        int idx = tid + k * 256;                // 4096 short4 = 128 d x 32
        int d = idx >> 5, j4 = idx & 31;
        *(short4_t*)&TT16[((size_t)(b * Lq + d)) * Lq + j4 * 4] =
            *(short4_t*)&lds[d * 132 + j4 * 4];
    }
}

// ---------------- k3: A = (E@Qm)*rsInv, Bm = (E@Tm)*rsInv, write [C,A,C*A,C*Bm] ----------------
// grid (Lc/64, B). wave w: i-subtile, 8 d-subtiles x {Q,T}.
__global__ __launch_bounds__(256) void k3_out(
    const short* __restrict__ E16, const short* __restrict__ QT16,
    const short* __restrict__ TT16, const float* __restrict__ rowsumInv,
    const float* __restrict__ C, float* __restrict__ out)
{
    int b = blockIdx.y, i0 = blockIdx.x * 64;
    int tid = threadIdx.x, w = tid >> 6, lane = tid & 63;
    int lm = lane & 15, quad = lane >> 4;
    int iw = i0 + w * 16;

    f32x4 accQ[8], accT[8];
    #pragma unroll
    for (int t = 0; t < 8; ++t) { accQ[t] = (f32x4){0.f,0.f,0.f,0.f}; accT[t] = (f32x4){0.f,0.f,0.f,0.f}; }

    const short8_t* Arow = (const short8_t*)(E16 + ((size_t)(b * Lc + iw + lm)) * Lq);
    #pragma unroll
    for (int ks = 0; ks < 4; ++ks) {
        short8_t a = Arow[ks * 4 + quad];
        int ko = ks * 32 + quad * 8;
        #pragma unroll
        for (int dt = 0; dt < 8; ++dt) {
            short8_t bq = *(const short8_t*)&QT16[((size_t)(b * Lq + dt * 16 + lm)) * Lq + ko];
            accQ[dt] = __builtin_amdgcn_mfma_f32_16x16x32_bf16(a, bq, accQ[dt], 0, 0, 0);
            short8_t bt = *(const short8_t*)&TT16[((size_t)(b * Lq + dt * 16 + lm)) * Lq + ko];
            accT[dt] = __builtin_amdgcn_mfma_f32_16x16x32_bf16(a, bt, accT[dt], 0, 0, 0);
        }
    }

    float rs[4];
    #pragma unroll
    for (int r = 0; r < 4; ++r) rs[r] = rowsumInv[b * Lc + iw + quad * 4 + r];

    #pragma unroll
    for (int dt = 0; dt < 8; ++dt) {
        int d = dt * 16 + lm;
        #pragma unroll
        for (int r = 0; r < 4; ++r) {
            int i = iw + quad * 4 + r;
            float av = accQ[dt][r] * rs[r];
            float bm = accT[dt][r] * rs[r];
            float cv = C[((size_t)(b * Lc + i)) * Dd + d];
            size_t base = ((size_t)(b * Lc + i)) * (4 * Dd);
            out[base + 0 * Dd + d] = cv;
            out[base + 1 * Dd + d] = av;
            out[base + 2 * Dd + d] = cv * av;
            out[base + 3 * Dd + d] = cv * bm;
        }
    }
}

extern "C" void kernel_launch(void* const* d_in, const int* in_sizes, int n_in,
                              void* d_out, int out_size, void* d_ws, size_t ws_size,
                              hipStream_t stream) {
    const float* C     = (const float*)d_in[0];
    const float* Q     = (const float*)d_in[1];
    const int*   Cmask = (const int*)d_in[2];
    const int*   Qmask = (const int*)d_in[3];
    const float* w_c   = (const float*)d_in[4];
    const float* w_q   = (const float*)d_in[5];
    const float* w_mul = (const float*)d_in[6];
    const float* bias  = (const float*)d_in[7];
    float* out = (float*)d_out;

    // workspace carve-up
    char* p = (char*)d_ws;
    const size_t NE = (size_t)Bn * Lc * Lq;   // 8.4M
    const size_t ND = (size_t)Bn * Lc * Dd;   // 8.4M
    const size_t NQ = (size_t)Bn * Lq * Dd;   // 1M
    short* E16   = (short*)p; p += NE * 2;
    short* ET16  = (short*)p; p += NE * 2;
    short* Cw16  = (short*)p; p += ND * 2;
    short* CT16  = (short*)p; p += ND * 2;
    short* Q16   = (short*)p; p += NQ * 2;
    short* QT16  = (short*)p; p += NQ * 2;
    short* TT16  = (short*)p; p += NQ * 2;
    float* T32   = (float*)p; p += NQ * 4;
    float* colsum     = (float*)p; p += (size_t)Bn * Lq * 4;
    float* rowsumInv  = (float*)p; p += (size_t)Bn * Lc * 4;
    float* s0c        = (float*)p; p += (size_t)Bn * Lc * 4;
    float* s1q        = (float*)p; p += (size_t)Bn * Lq * 4;

    hipMemsetAsync(colsum, 0, (size_t)Bn * Lq * 4, stream);
    hipMemsetAsync(T32, 0, NQ * 4, stream);

    kP_prep<<<dim3(17, Bn), 256, 0, stream>>>(C, Q, Cmask, Qmask, w_c, w_q, w_mul,
                                              Cw16, CT16, Q16, QT16, s0c, s1q);
    k1_scores<<<dim3(Lc / 64, Bn), 256, 0, stream>>>(Cw16, Q16, Cmask, Qmask, s0c, s1q, bias,
                                                     E16, ET16, colsum, rowsumInv);
    k2_T<<<dim3(4, Bn), 256, 0, stream>>>(ET16, CT16, T32);
    k2b_finish<<<dim3(Bn), 256, 0, stream>>>(T32, colsum, Qmask, TT16);
    k3_out<<<dim3(Lc / 64, Bn), 256, 0, stream>>>(E16, QT16, TT16, rowsumInv, C, out);
}